// Round 1
// baseline (1150.587 us; speedup 1.0000x reference)
//
#include <hip/hip_runtime.h>
#include <cstdint>
#include <cstddef>

#define BN_EPS 1e-5f

__device__ __forceinline__ float elu_f(float v){ return v > 0.f ? v : expm1f(v); }
__device__ __forceinline__ float leaky_f(float v){ return v > 0.f ? v : 0.2f*v; }

__device__ __forceinline__ float warp_max(float v){
#pragma unroll
  for(int o=32;o>0;o>>=1) v = fmaxf(v, __shfl_xor(v, o));
  return v;
}
__device__ __forceinline__ float warp_sum(float v){
#pragma unroll
  for(int o=32;o>0;o>>=1) v += __shfl_xor(v, o);
  return v;
}

// ---------------- graph preprocessing: CSR by dst ----------------

__global__ void count_deg_kernel(const int* __restrict__ dst, int E, int* __restrict__ cnt){
  int i = blockIdx.x*blockDim.x + threadIdx.x;
  if(i < E) atomicAdd(&cnt[dst[i]], 1);
}

// single-block exclusive scan over cnt[0..n) -> rowptr[0..n]
__global__ void scan_kernel(const int* __restrict__ cnt, int n, int* __restrict__ rowptr){
  __shared__ int buf[2][1024];
  __shared__ int carry_s;
  int tid = threadIdx.x;
  if(tid == 0) carry_s = 0;
  __syncthreads();
  for(int base = 0; base < n; base += 1024){
    int i = base + tid;
    int v = (i < n) ? cnt[i] : 0;
    int cur = 0;
    buf[0][tid] = v;
    __syncthreads();
    for(int off = 1; off < 1024; off <<= 1){
      int val = buf[cur][tid] + ((tid >= off) ? buf[cur][tid-off] : 0);
      cur ^= 1;
      buf[cur][tid] = val;
      __syncthreads();
    }
    if(i < n) rowptr[i] = carry_s + buf[cur][tid] - v;   // exclusive
    __syncthreads();
    if(tid == 1023) carry_s += buf[cur][1023];
    __syncthreads();
  }
  if(tid == 0) rowptr[n] = carry_s;
}

__global__ void dinv_kernel(const int* __restrict__ cnt, float* __restrict__ dinv, int N){
  int i = blockIdx.x*blockDim.x + threadIdx.x;
  if(i < N) dinv[i] = rsqrtf((float)cnt[i] + 1.0f);   // deg includes self loop
}

__global__ void scatter_kernel(const int* __restrict__ src, const int* __restrict__ dst, int E,
                               const int* __restrict__ rowptr, int* __restrict__ fill, int* __restrict__ col){
  int i = blockIdx.x*blockDim.x + threadIdx.x;
  if(i < E){
    int d = dst[i];
    int pos = rowptr[d] + atomicAdd(&fill[d], 1);
    col[pos] = src[i];
  }
}

// ---------------- tiled fp32 GEMM, out width = 128 ----------------
// out[N,128] = act(A[N,K] @ W[K,128] + bias)

template<int ACT>
__global__ __launch_bounds__(256) void gemm_n128(const float* __restrict__ A, const float* __restrict__ W,
    const float* __restrict__ bias, float* __restrict__ out, int N, int K)
{
  __shared__ float As[16][128];   // As[k][r]
  __shared__ float Bs[16][128];   // Bs[k][c]
  int row0 = blockIdx.x*128;
  int t = threadIdx.x;
  int tx = t & 15, ty = t >> 4;
  float acc[8][8];
#pragma unroll
  for(int q=0;q<8;q++)
#pragma unroll
    for(int j=0;j<8;j++) acc[q][j]=0.f;

  int ar = t >> 1, akb = (t & 1)*8;      // A-load: row ar, k-chunk akb..akb+7
  int bk = t >> 4, bcb = (t & 15)*8;     // B-load: k row bk, cols bcb..bcb+7

  for(int k0 = 0; k0 < K; k0 += 16){
    {
      int row = row0 + ar;
      if(row < N){
#pragma unroll
        for(int q=0;q<8;q++){
          int k = k0 + akb + q;
          As[akb+q][ar] = (k < K) ? A[(size_t)row*K + k] : 0.f;
        }
      } else {
#pragma unroll
        for(int q=0;q<8;q++) As[akb+q][ar] = 0.f;
      }
    }
    {
      int k = k0 + bk;
      if(k < K){
#pragma unroll
        for(int q=0;q<8;q++) Bs[bk][bcb+q] = W[(size_t)k*128 + bcb + q];
      } else {
#pragma unroll
        for(int q=0;q<8;q++) Bs[bk][bcb+q] = 0.f;
      }
    }
    __syncthreads();
#pragma unroll
    for(int k=0;k<16;k++){
      float a[8], b[8];
#pragma unroll
      for(int q=0;q<8;q++) a[q] = As[k][ty*8+q];
#pragma unroll
      for(int q=0;q<8;q++) b[q] = Bs[k][tx*8+q];
#pragma unroll
      for(int q=0;q<8;q++)
#pragma unroll
        for(int j=0;j<8;j++) acc[q][j] += a[q]*b[j];
    }
    __syncthreads();
  }
#pragma unroll
  for(int q=0;q<8;q++){
    int row = row0 + ty*8 + q;
    if(row < N){
#pragma unroll
      for(int j=0;j<8;j++){
        int c = tx*8 + j;
        float v = acc[q][j] + (bias ? bias[c] : 0.f);
        if(ACT) v = elu_f(v);
        out[(size_t)row*128 + c] = v;
      }
    }
  }
}

// ---------------- GCN aggregation + BN1 + ELU ----------------

__global__ __launch_bounds__(128) void gcn_agg(const float* __restrict__ hw, const int* __restrict__ rowptr,
    const int* __restrict__ col, const float* __restrict__ dinv, const float* __restrict__ b,
    const float* __restrict__ bg, const float* __restrict__ bb,
    const float* __restrict__ bm, const float* __restrict__ bv,
    float* __restrict__ h1, int N)
{
  int i = blockIdx.x;
  int c = threadIdx.x;
  float di = dinv[i];
  int beg = rowptr[i], end = rowptr[i+1];
  float acc = hw[(size_t)i*128 + c] * di;   // self loop (×di again at end)
  for(int p = beg; p < end; p++){
    int s = col[p];
    acc += hw[(size_t)s*128 + c] * dinv[s];
  }
  float v = acc*di + b[c];
  float scale = bg[c]*rsqrtf(bv[c] + BN_EPS);
  v = (v - bm[c])*scale + bb[c];
  h1[(size_t)i*128 + c] = elu_f(v);
}

// ---------------- GAT attention scalars ----------------

__global__ __launch_bounds__(128) void att_kernel(const float* __restrict__ g, const float* __restrict__ att_src,
    const float* __restrict__ att_dst, float* __restrict__ a_src, float* __restrict__ a_dst, int N)
{
  int i = blockIdx.x, t = threadIdx.x;   // t = head*64 + ch
  float gv = g[(size_t)i*128 + t];
  float s1 = gv*att_src[t];
  float s2 = gv*att_dst[t];
  s1 = warp_sum(s1); s2 = warp_sum(s2);
  if((t & 63) == 0){ int h = t >> 6; a_src[2*i+h] = s1; a_dst[2*i+h] = s2; }
}

// ---------------- GAT: softmax + weighted aggregation + BN2 + ELU ----------------

__global__ __launch_bounds__(128) void gat_agg(const float* __restrict__ g, const float* __restrict__ a_src,
    const float* __restrict__ a_dst, const int* __restrict__ rowptr, const int* __restrict__ col,
    const float* __restrict__ b_gat, const float* __restrict__ bg, const float* __restrict__ bb,
    const float* __restrict__ bm, const float* __restrict__ bv, float* __restrict__ h2, int N)
{
  __shared__ float red[2][2];
  int i = blockIdx.x;
  int t = threadIdx.x;
  int beg = rowptr[i], end = rowptr[i+1];
  float ad0 = a_dst[2*i], ad1 = a_dst[2*i+1];
  float es0 = leaky_f(a_src[2*i]   + ad0);   // self-loop logits
  float es1 = leaky_f(a_src[2*i+1] + ad1);

  // phase 1: per-head max over neighbors + self
  float m0 = es0, m1 = es1;
  for(int p = beg + t; p < end; p += 128){
    int s = col[p];
    m0 = fmaxf(m0, leaky_f(a_src[2*s]   + ad0));
    m1 = fmaxf(m1, leaky_f(a_src[2*s+1] + ad1));
  }
  m0 = warp_max(m0); m1 = warp_max(m1);
  if((t & 63) == 0){ red[t>>6][0] = m0; red[t>>6][1] = m1; }
  __syncthreads();
  float M0 = fmaxf(red[0][0], red[1][0]);
  float M1 = fmaxf(red[0][1], red[1][1]);
  __syncthreads();

  // phase 2: denominators
  float d0 = (t == 0) ? expf(es0 - M0) : 0.f;
  float d1 = (t == 0) ? expf(es1 - M1) : 0.f;
  for(int p = beg + t; p < end; p += 128){
    int s = col[p];
    d0 += expf(leaky_f(a_src[2*s]   + ad0) - M0);
    d1 += expf(leaky_f(a_src[2*s+1] + ad1) - M1);
  }
  d0 = warp_sum(d0); d1 = warp_sum(d1);
  if((t & 63) == 0){ red[t>>6][0] = d0; red[t>>6][1] = d1; }
  __syncthreads();
  float D0 = red[0][0] + red[1][0] + 1e-16f;
  float D1 = red[0][1] + red[1][1] + 1e-16f;

  // phase 3: weighted feature sum; thread t owns channel t (head = t>>6)
  int hh = t >> 6;
  float Mh  = hh ? M1 : M0;
  float Dh  = hh ? D1 : D0;
  float adh = hh ? ad1 : ad0;
  float esh = hh ? es1 : es0;
  float acc = expf(esh - Mh) * g[(size_t)i*128 + t];
  for(int p = beg; p < end; p++){
    int s = col[p];
    float w = expf(leaky_f(a_src[2*s + hh] + adh) - Mh);
    acc += w * g[(size_t)s*128 + t];
  }
  float v = acc/Dh + b_gat[t];
  float scale = bg[t]*rsqrtf(bv[t] + BN_EPS);
  v = (v - bm[t])*scale + bb[t];
  h2[(size_t)i*128 + t] = elu_f(v);
}

// ---------------- SAGE mean aggregation (no self loops) ----------------

__global__ __launch_bounds__(128) void sage_mean(const float* __restrict__ h2, const int* __restrict__ rowptr,
    const int* __restrict__ col, float* __restrict__ mean_nb, int N)
{
  int i = blockIdx.x, t = threadIdx.x;
  int beg = rowptr[i], end = rowptr[i+1];
  float acc = 0.f;
  for(int p = beg; p < end; p++)
    acc += h2[(size_t)col[p]*128 + t];
  float inv = 1.f/fmaxf((float)(end - beg), 1.f);
  mean_nb[(size_t)i*128 + t] = acc*inv;
}

// ---------------- fused SAGE/residual GEMMs -> h3 ----------------
// h3 = elu( bn3(A1@W1 + A2@W2 + b_sage) + A3@W3 + b_res ),  all K=128, 64 cols

__global__ __launch_bounds__(256) void gemm_fused_sage(
    const float* __restrict__ A1, const float* __restrict__ A2, const float* __restrict__ A3,
    const float* __restrict__ W1, const float* __restrict__ W2, const float* __restrict__ W3,
    const float* __restrict__ b_sage, const float* __restrict__ b_res,
    const float* __restrict__ bg, const float* __restrict__ bb,
    const float* __restrict__ bm, const float* __restrict__ bv,
    float* __restrict__ h3, int N)
{
  __shared__ float As[3][16][128];
  __shared__ float Bs[3][16][64];
  int row0 = blockIdx.x*128;
  int t = threadIdx.x;
  int tx = t & 15, ty = t >> 4;
  float acc12[8][4], acc3[8][4];
#pragma unroll
  for(int q=0;q<8;q++)
#pragma unroll
    for(int j=0;j<4;j++){ acc12[q][j]=0.f; acc3[q][j]=0.f; }

  int ar = t >> 1, akb = (t & 1)*8;
  int bk = t >> 4, bcb = (t & 15)*4;
  const float* Aps[3] = {A1, A2, A3};
  const float* Wps[3] = {W1, W2, W3};

  for(int k0 = 0; k0 < 128; k0 += 16){
#pragma unroll
    for(int pp=0;pp<3;pp++){
      const float* Ap = Aps[pp];
      int row = row0 + ar;
      if(row < N){
#pragma unroll
        for(int q=0;q<8;q++) As[pp][akb+q][ar] = Ap[(size_t)row*128 + k0 + akb + q];
      } else {
#pragma unroll
        for(int q=0;q<8;q++) As[pp][akb+q][ar] = 0.f;
      }
      const float* Wp = Wps[pp];
#pragma unroll
      for(int q=0;q<4;q++) Bs[pp][bk][bcb+q] = Wp[(size_t)(k0+bk)*64 + bcb + q];
    }
    __syncthreads();
#pragma unroll
    for(int k=0;k<16;k++){
      float a1[8],a2[8],a3[8],b1[4],b2[4],b3[4];
#pragma unroll
      for(int q=0;q<8;q++){ a1[q]=As[0][k][ty*8+q]; a2[q]=As[1][k][ty*8+q]; a3[q]=As[2][k][ty*8+q]; }
#pragma unroll
      for(int j=0;j<4;j++){ b1[j]=Bs[0][k][tx*4+j]; b2[j]=Bs[1][k][tx*4+j]; b3[j]=Bs[2][k][tx*4+j]; }
#pragma unroll
      for(int q=0;q<8;q++)
#pragma unroll
        for(int j=0;j<4;j++){
          acc12[q][j] += a1[q]*b1[j] + a2[q]*b2[j];
          acc3[q][j]  += a3[q]*b3[j];
        }
    }
    __syncthreads();
  }
#pragma unroll
  for(int q=0;q<8;q++){
    int row = row0 + ty*8 + q;
    if(row < N){
#pragma unroll
      for(int j=0;j<4;j++){
        int c = tx*4 + j;
        float scale = bg[c]*rsqrtf(bv[c] + BN_EPS);
        float v = (acc12[q][j] + b_sage[c] - bm[c])*scale + bb[c] + acc3[q][j] + b_res[c];
        h3[(size_t)row*64 + c] = elu_f(v);
      }
    }
  }
}

// ---------------- classifier: out = elu(h3@w1+b1)@w2 + b2 ----------------

__global__ __launch_bounds__(256) void classifier_kernel(const float* __restrict__ h3,
    const float* __restrict__ w1, const float* __restrict__ b1,
    const float* __restrict__ w2, const float* __restrict__ b2,
    float* __restrict__ out, int N)
{
  __shared__ float hs[8][64];
  __shared__ float zs[8][32];
  int node0 = blockIdx.x*8;
  int t = threadIdx.x;
#pragma unroll
  for(int q=0;q<2;q++){
    int e = t + q*256;
    int r = e >> 6, c = e & 63;
    int nd = node0 + r;
    hs[r][c] = (nd < N) ? h3[(size_t)nd*64 + c] : 0.f;
  }
  __syncthreads();
  int nn = t >> 5, ln = t & 31;
  float acc = b1[ln];
#pragma unroll
  for(int k=0;k<64;k++) acc += hs[nn][k]*w1[k*32 + ln];
  zs[nn][ln] = elu_f(acc);
  __syncthreads();
  int node = node0 + nn;
  if(ln < 2 && node < N){
    float o = b2[ln];
#pragma unroll
    for(int k=0;k<32;k++) o += zs[nn][k]*w2[k*2 + ln];
    out[(size_t)node*2 + ln] = o;
  }
}

// ---------------- launch ----------------

extern "C" void kernel_launch(void* const* d_in, const int* in_sizes, int n_in,
                              void* d_out, int out_size, void* d_ws, size_t ws_size,
                              hipStream_t stream)
{
  (void)n_in; (void)out_size; (void)ws_size;
  const float* x      = (const float*)d_in[0];
  const int*   ei     = (const int*)  d_in[1];
  const float* w_in   = (const float*)d_in[2];
  const float* b_in   = (const float*)d_in[3];
  const float* w_gcn  = (const float*)d_in[4];
  const float* b_gcn  = (const float*)d_in[5];
  const float* bn1_g  = (const float*)d_in[6];
  const float* bn1_b  = (const float*)d_in[7];
  const float* bn1_m  = (const float*)d_in[8];
  const float* bn1_v  = (const float*)d_in[9];
  const float* w_gat  = (const float*)d_in[10];
  const float* att_s  = (const float*)d_in[11];
  const float* att_d  = (const float*)d_in[12];
  const float* b_gat  = (const float*)d_in[13];
  const float* bn2_g  = (const float*)d_in[14];
  const float* bn2_b  = (const float*)d_in[15];
  const float* bn2_m  = (const float*)d_in[16];
  const float* bn2_v  = (const float*)d_in[17];
  const float* w_sl   = (const float*)d_in[18];
  const float* b_sage = (const float*)d_in[19];
  const float* w_sr   = (const float*)d_in[20];
  const float* bn3_g  = (const float*)d_in[21];
  const float* bn3_b  = (const float*)d_in[22];
  const float* bn3_m  = (const float*)d_in[23];
  const float* bn3_v  = (const float*)d_in[24];
  const float* w_res  = (const float*)d_in[25];
  const float* b_res  = (const float*)d_in[26];
  const float* w_c1   = (const float*)d_in[27];
  const float* b_c1   = (const float*)d_in[28];
  const float* w_c2   = (const float*)d_in[29];
  const float* b_c2   = (const float*)d_in[30];

  const int F_IN = 165;
  int N = in_sizes[0]/F_IN;
  int E = in_sizes[1]/2;
  const int* srcp = ei;
  const int* dstp = ei + E;

  char* p = (char*)d_ws;
  float* h     = (float*)p; p += (size_t)N*128*4;   // residual
  float* bufA  = (float*)p; p += (size_t)N*128*4;   // hw -> g -> mean_nb
  float* bufB  = (float*)p; p += (size_t)N*128*4;   // h1 -> h2
  float* h3b   = (float*)p; p += (size_t)N*64*4;
  float* dinv  = (float*)p; p += (size_t)N*4;
  float* a_src = (float*)p; p += (size_t)N*2*4;
  float* a_dst = (float*)p; p += (size_t)N*2*4;
  int* cnt     = (int*)p;   p += (size_t)N*4;
  int* rowptr  = (int*)p;   p += (size_t)(N+1)*4;
  int* fill    = (int*)p;   p += (size_t)N*4;
  int* col     = (int*)p;   p += (size_t)E*4;

  hipMemsetAsync(cnt,  0, (size_t)N*4, stream);
  hipMemsetAsync(fill, 0, (size_t)N*4, stream);

  count_deg_kernel<<<(E+255)/256, 256, 0, stream>>>(dstp, E, cnt);
  scan_kernel<<<1, 1024, 0, stream>>>(cnt, N, rowptr);
  dinv_kernel<<<(N+255)/256, 256, 0, stream>>>(cnt, dinv, N);
  scatter_kernel<<<(E+255)/256, 256, 0, stream>>>(srcp, dstp, E, rowptr, fill, col);

  int gblk = (N + 127)/128;
  // h = elu(x @ w_in + b_in)
  gemm_n128<1><<<gblk, 256, 0, stream>>>(x, w_in, b_in, h, N, F_IN);
  // hw = h @ w_gcn
  gemm_n128<0><<<gblk, 256, 0, stream>>>(h, w_gcn, nullptr, bufA, N, 128);
  // h1 = elu(bn1(gcn_agg(hw) + b_gcn))
  gcn_agg<<<N, 128, 0, stream>>>(bufA, rowptr, col, dinv, b_gcn, bn1_g, bn1_b, bn1_m, bn1_v, bufB, N);
  // g = h1 @ w_gat
  gemm_n128<0><<<gblk, 256, 0, stream>>>(bufB, w_gat, nullptr, bufA, N, 128);
  // attention scalars
  att_kernel<<<N, 128, 0, stream>>>(bufA, att_s, att_d, a_src, a_dst, N);
  // h2 = elu(bn2(gat_agg(g) + b_gat))   (writes over h1)
  gat_agg<<<N, 128, 0, stream>>>(bufA, a_src, a_dst, rowptr, col, b_gat, bn2_g, bn2_b, bn2_m, bn2_v, bufB, N);
  // mean_nb (writes over g)
  sage_mean<<<N, 128, 0, stream>>>(bufB, rowptr, col, bufA, N);
  // h3 = elu(bn3(mean_nb@w_sl + h2@w_sr + b_sage) + residual@w_res + b_res)
  gemm_fused_sage<<<gblk, 256, 0, stream>>>(bufA, bufB, h, w_sl, w_sr, w_res,
                                            b_sage, b_res, bn3_g, bn3_b, bn3_m, bn3_v, h3b, N);
  // out = elu(h3@w_c1+b_c1)@w_c2 + b_c2
  classifier_kernel<<<(N+7)/8, 256, 0, stream>>>(h3b, w_c1, b_c1, w_c2, b_c2, (float*)d_out, N);
}

// Round 2
// 514.063 us; speedup vs baseline: 2.2382x; 2.2382x over previous
//
#include <hip/hip_runtime.h>
#include <cstdint>
#include <cstddef>

#define BN_EPS 1e-5f

typedef __attribute__((ext_vector_type(8))) short short8v;
typedef __attribute__((ext_vector_type(4))) float float4v;
typedef __attribute__((ext_vector_type(4))) unsigned int uint4v;
typedef unsigned int uint32;
typedef unsigned short ushort16;

__device__ __forceinline__ float elu_f(float v){ return v > 0.f ? v : expm1f(v); }
__device__ __forceinline__ float leaky_f(float v){ return v > 0.f ? v : 0.2f*v; }
__device__ __forceinline__ uint32 f2bf(float f){
  uint32 b = __float_as_uint(f);
  return (b + 0x7fffu + ((b >> 16) & 1u)) >> 16;        // RNE
}
__device__ __forceinline__ float bflo(uint32 u){ return __uint_as_float(u << 16); }
__device__ __forceinline__ float bfhi(uint32 u){ return __uint_as_float(u & 0xffff0000u); }

// ---------------- graph preprocessing: CSR by dst ----------------

__global__ void count_deg_kernel(const int* __restrict__ dst, int E, int* __restrict__ cnt){
  int i = blockIdx.x*blockDim.x + threadIdx.x;
  if(i < E) atomicAdd(&cnt[dst[i]], 1);
}

__global__ __launch_bounds__(1024) void scan_kernel(const int* __restrict__ cnt, int n, int* __restrict__ rowptr){
  __shared__ int wsum[16];
  __shared__ int carry_s;
  int tid = threadIdx.x;
  int lane = tid & 63, w = tid >> 6;
  if(tid == 0) carry_s = 0;
  __syncthreads();
  for(int base = 0; base < n; base += 1024){
    int i = base + tid;
    int v = (i < n) ? cnt[i] : 0;
    int sv = v;
#pragma unroll
    for(int o = 1; o < 64; o <<= 1){
      int u = __shfl_up(sv, o);
      if(lane >= o) sv += u;
    }
    if(lane == 63) wsum[w] = sv;
    __syncthreads();                       // wsum ready, carry_s stable
    int carry = carry_s;
    int woff = 0;
#pragma unroll
    for(int q = 0; q < 16; q++) woff += (q < w) ? wsum[q] : 0;
    if(i < n) rowptr[i] = carry + woff + sv - v;   // exclusive
    __syncthreads();                       // all reads done
    if(tid == 1023) carry_s = carry + woff + sv;
    __syncthreads();
  }
  if(tid == 0) rowptr[n] = carry_s;
}

__global__ void dinv_kernel(const int* __restrict__ cnt, float* __restrict__ dinv, int N){
  int i = blockIdx.x*blockDim.x + threadIdx.x;
  if(i < N) dinv[i] = rsqrtf((float)cnt[i] + 1.0f);   // deg includes self loop
}

__global__ void scatter_kernel(const int* __restrict__ src, const int* __restrict__ dst, int E,
                               const int* __restrict__ rowptr, int* __restrict__ fill, int* __restrict__ col){
  int i = blockIdx.x*blockDim.x + threadIdx.x;
  if(i < E){
    int d = dst[i];
    int pos = rowptr[d] + atomicAdd(&fill[d], 1);
    col[pos] = src[i];
  }
}

// ---------------- x -> bf16, K padded 165 -> 192 ----------------

__global__ __launch_bounds__(192) void cvt_x(const float* __restrict__ x, ushort16* __restrict__ xb, int N){
  int i = blockIdx.x, t = threadIdx.x;
  float v = (t < 165) ? x[(size_t)i*165 + t] : 0.f;
  xb[(size_t)i*192 + t] = (ushort16)f2bf(v);
}

// ---------------- weight packing: packed[kgrp][col][8] bf16 ----------------

__global__ void pack_w(const float* __restrict__ W, int K, int NOUT, int kbase, int krange,
                       const float* __restrict__ scale, ushort16* __restrict__ out){
  int idx = blockIdx.x*blockDim.x + threadIdx.x;
  if(idx >= krange*NOUT) return;
  int k = idx / NOUT, c = idx - (idx/NOUT)*NOUT;
  float v = (k < K) ? W[(size_t)k*NOUT + c] : 0.f;
  if(scale) v *= scale[c];
  int pk = kbase + k;
  out[(size_t)(pk >> 3)*NOUT*8 + (size_t)c*8 + (pk & 7)] = (ushort16)f2bf(v);
}

// bn3 scale + combined bias for the fused SAGE epilogue
__global__ void prep3(const float* __restrict__ bg, const float* __restrict__ bb,
                      const float* __restrict__ bm, const float* __restrict__ bv,
                      const float* __restrict__ b_sage, const float* __restrict__ b_res,
                      float* __restrict__ s3, float* __restrict__ bias3){
  int c = threadIdx.x;   // 64
  float s = bg[c]*rsqrtf(bv[c] + BN_EPS);
  s3[c] = s;
  bias3[c] = (b_sage[c] - bm[c])*s + bb[c] + b_res[c];
}

// ---------------- MFMA bf16 GEMM ----------------
// out[M x NOUT] = epi(A[M x K] @ W)   A bf16 row-major (lda elements), W packed in global.
// EPI: 0 = raw -> bf16, 1 = bias+elu -> bf16, 2 = bias+elu -> fp32
// NOUT=128: 4 waves 2x2, tile 128x128. NOUT=64: 4 waves 4x1, tile 256x64.

template<int KSTEPS, int NOUT, int EPI>
__global__ __launch_bounds__(256) void mfma_gemm(
    const ushort16* __restrict__ A, int lda,
    const uint4v* __restrict__ pw,
    const float* __restrict__ bias,
    void* __restrict__ out, int ldo, int N)
{
  constexpr int LDSV = KSTEPS*4*NOUT;         // uint4 entries (16 B each)
  __shared__ uint4v wlds[LDSV];
  int t = threadIdx.x;
#pragma unroll
  for(int q = 0; q < LDSV/256; q++)
    wlds[q*256 + t] = pw[q*256 + t];
  __syncthreads();

  int wid = t >> 6, lane = t & 63;
  int wm, wn;
  if(NOUT == 128){ wm = wid >> 1; wn = wid & 1; } else { wm = wid; wn = 0; }
  constexpr int MTILE = (NOUT == 128) ? 128 : 256;
  long row0 = (long)blockIdx.x*MTILE + wm*64;
  int l15 = lane & 15, lk = lane >> 4;
  int wn64 = wn*64;
  const ushort16* wl = (const ushort16*)wlds;

  float4v acc[4][4];
#pragma unroll
  for(int fm = 0; fm < 4; fm++)
#pragma unroll
    for(int fn = 0; fn < 4; fn++) acc[fm][fn] = (float4v){0.f,0.f,0.f,0.f};

  const ushort16* abase[4];
#pragma unroll
  for(int fm = 0; fm < 4; fm++){
    long r = row0 + fm*16 + l15;
    if(r > (long)N - 1) r = (long)N - 1;
    abase[fm] = A + r*(size_t)lda + lk*8;
  }

  short8v a[4];
#pragma unroll
  for(int fm = 0; fm < 4; fm++) a[fm] = *(const short8v*)(abase[fm]);

#pragma unroll
  for(int ks = 0; ks < KSTEPS; ks++){
    short8v b[4];
#pragma unroll
    for(int fn = 0; fn < 4; fn++){
      int c = wn64 + fn*16 + l15;
      b[fn] = *(const short8v*)(wl + ((size_t)((ks*4 + lk)*NOUT + c))*8);
    }
    short8v an[4];
    if(ks + 1 < KSTEPS){
#pragma unroll
      for(int fm = 0; fm < 4; fm++) an[fm] = *(const short8v*)(abase[fm] + (ks + 1)*32);
    }
#pragma unroll
    for(int fm = 0; fm < 4; fm++)
#pragma unroll
      for(int fn = 0; fn < 4; fn++)
        acc[fm][fn] = __builtin_amdgcn_mfma_f32_16x16x32_bf16(a[fm], b[fn], acc[fm][fn], 0, 0, 0);
    if(ks + 1 < KSTEPS){
#pragma unroll
      for(int fm = 0; fm < 4; fm++) a[fm] = an[fm];
    }
  }

  // C/D layout: col = lane&15, row = (lane>>4)*4 + reg  [m89 verified]
#pragma unroll
  for(int fm = 0; fm < 4; fm++){
#pragma unroll
    for(int rr = 0; rr < 4; rr++){
      long r = row0 + fm*16 + lk*4 + rr;
      if(r < N){
#pragma unroll
        for(int fn = 0; fn < 4; fn++){
          int c = wn64 + fn*16 + l15;
          float v = acc[fm][fn][rr];
          if constexpr(EPI >= 1){ v += bias[c]; v = elu_f(v); }
          if constexpr(EPI == 2) ((float*)out)[r*(size_t)ldo + c] = v;
          else ((ushort16*)out)[r*(size_t)ldo + c] = (ushort16)f2bf(v);
        }
      }
    }
  }
}

// ---------------- GCN aggregation + BN1 + ELU (bf16 in/out, 2 ch/lane) ----------------

__global__ __launch_bounds__(64) void gcn_agg(const uint32* __restrict__ hw,   // stride 64 uints
    const int* __restrict__ rowptr, const int* __restrict__ col, const float* __restrict__ dinv,
    const float* __restrict__ b, const float* __restrict__ bg, const float* __restrict__ bb,
    const float* __restrict__ bm, const float* __restrict__ bv,
    uint32* __restrict__ h1, int N)
{
  int i = blockIdx.x, t = threadIdx.x;
  float di = dinv[i];
  int beg = rowptr[i], end = rowptr[i+1];
  uint32 u = hw[(size_t)i*64 + t];
  float a0 = bflo(u)*di, a1 = bfhi(u)*di;   // self loop
  for(int p = beg; p < end; p++){
    int s = col[p];
    float ds = dinv[s];
    uint32 w = hw[(size_t)s*64 + t];
    a0 += bflo(w)*ds; a1 += bfhi(w)*ds;
  }
  int c0 = 2*t, c1 = 2*t + 1;
  float v0 = a0*di + b[c0], v1 = a1*di + b[c1];
  v0 = elu_f((v0 - bm[c0])*(bg[c0]*rsqrtf(bv[c0] + BN_EPS)) + bb[c0]);
  v1 = elu_f((v1 - bm[c1])*(bg[c1]*rsqrtf(bv[c1] + BN_EPS)) + bb[c1]);
  h1[(size_t)i*64 + t] = f2bf(v0) | (f2bf(v1) << 16);
}

// ---------------- GAT attention scalars ----------------

__global__ __launch_bounds__(64) void att_kernel(const uint32* __restrict__ g,
    const float* __restrict__ att_s, const float* __restrict__ att_d,
    float* __restrict__ a_src, float* __restrict__ a_dst, int N)
{
  int i = blockIdx.x, t = threadIdx.x;
  uint32 u = g[(size_t)i*64 + t];
  float g0 = bflo(u), g1 = bfhi(u);
  float2 as2 = ((const float2*)att_s)[t];
  float2 ad2 = ((const float2*)att_d)[t];
  float s1 = g0*as2.x + g1*as2.y;
  float s2 = g0*ad2.x + g1*ad2.y;
#pragma unroll
  for(int o = 16; o > 0; o >>= 1){ s1 += __shfl_xor(s1, o); s2 += __shfl_xor(s2, o); }
  if((t & 31) == 0){ int h = t >> 5; a_src[2*i + h] = s1; a_dst[2*i + h] = s2; }
}

// ---------------- GAT softmax + weighted agg + BN2 + ELU ----------------
// writes h2 (bf16) into Acat[:,128:256]  (out pre-offset, stride 192 uints)

__global__ __launch_bounds__(64) void gat_agg(const uint32* __restrict__ g,   // stride 64
    const float* __restrict__ a_src, const float* __restrict__ a_dst,
    const int* __restrict__ rowptr, const int* __restrict__ col,
    const float* __restrict__ b_gat, const float* __restrict__ bg, const float* __restrict__ bb,
    const float* __restrict__ bm, const float* __restrict__ bv,
    uint32* __restrict__ h2out, int N)
{
  int i = blockIdx.x, t = threadIdx.x;
  int beg = rowptr[i], end = rowptr[i+1];
  float2 ad  = ((const float2*)a_dst)[i];
  float2 asv = ((const float2*)a_src)[i];
  float es0 = leaky_f(asv.x + ad.x), es1 = leaky_f(asv.y + ad.y);

  float m0 = es0, m1 = es1;
  for(int p = beg + t; p < end; p += 64){
    float2 a = ((const float2*)a_src)[col[p]];
    m0 = fmaxf(m0, leaky_f(a.x + ad.x));
    m1 = fmaxf(m1, leaky_f(a.y + ad.y));
  }
#pragma unroll
  for(int o = 32; o > 0; o >>= 1){ m0 = fmaxf(m0, __shfl_xor(m0, o)); m1 = fmaxf(m1, __shfl_xor(m1, o)); }

  float d0 = (t == 0) ? __expf(es0 - m0) : 0.f;
  float d1 = (t == 0) ? __expf(es1 - m1) : 0.f;
  for(int p = beg + t; p < end; p += 64){
    float2 a = ((const float2*)a_src)[col[p]];
    d0 += __expf(leaky_f(a.x + ad.x) - m0);
    d1 += __expf(leaky_f(a.y + ad.y) - m1);
  }
#pragma unroll
  for(int o = 32; o > 0; o >>= 1){ d0 += __shfl_xor(d0, o); d1 += __shfl_xor(d1, o); }
  d0 += 1e-16f; d1 += 1e-16f;

  int h = t >> 5;
  float Mh = h ? m1 : m0, Dh = h ? d1 : d0;
  float adh = h ? ad.y : ad.x, esh = h ? es1 : es0;
  uint32 u = g[(size_t)i*64 + t];
  float ws = __expf(esh - Mh);
  float acc0 = ws*bflo(u), acc1 = ws*bfhi(u);
  for(int p = beg; p < end; p++){
    int s = col[p];
    float w = __expf(leaky_f(a_src[2*s + h] + adh) - Mh);
    uint32 v = g[(size_t)s*64 + t];
    acc0 += w*bflo(v); acc1 += w*bfhi(v);
  }
  int c0 = 2*t, c1 = 2*t + 1;
  float v0 = acc0/Dh + b_gat[c0], v1 = acc1/Dh + b_gat[c1];
  v0 = elu_f((v0 - bm[c0])*(bg[c0]*rsqrtf(bv[c0] + BN_EPS)) + bb[c0]);
  v1 = elu_f((v1 - bm[c1])*(bg[c1]*rsqrtf(bv[c1] + BN_EPS)) + bb[c1]);
  h2out[(size_t)i*192 + t] = f2bf(v0) | (f2bf(v1) << 16);
}

// ---------------- SAGE mean (no self loops), h2 -> mean_nb, both inside Acat ----------------

__global__ __launch_bounds__(64) void sage_mean(const uint32* __restrict__ h2,  // pre-offset +64, stride 192
    const int* __restrict__ rowptr, const int* __restrict__ col,
    uint32* __restrict__ mout, int N)                                           // stride 192
{
  int i = blockIdx.x, t = threadIdx.x;
  int beg = rowptr[i], end = rowptr[i+1];
  float a0 = 0.f, a1 = 0.f;
  for(int p = beg; p < end; p++){
    uint32 u = h2[(size_t)col[p]*192 + t];
    a0 += bflo(u); a1 += bfhi(u);
  }
  float inv = 1.f/fmaxf((float)(end - beg), 1.f);
  mout[(size_t)i*192 + t] = f2bf(a0*inv) | (f2bf(a1*inv) << 16);
}

// ---------------- classifier: out = elu(h3@w1+b1)@w2 + b2 ----------------

__global__ __launch_bounds__(256) void classifier_kernel(const float* __restrict__ h3,
    const float* __restrict__ w1, const float* __restrict__ b1,
    const float* __restrict__ w2, const float* __restrict__ b2,
    float* __restrict__ out, int N)
{
  __shared__ float hs[8][64];
  __shared__ float zs[8][32];
  int node0 = blockIdx.x*8;
  int t = threadIdx.x;
#pragma unroll
  for(int q = 0; q < 2; q++){
    int e = t + q*256;
    int r = e >> 6, c = e & 63;
    int nd = node0 + r;
    hs[r][c] = (nd < N) ? h3[(size_t)nd*64 + c] : 0.f;
  }
  __syncthreads();
  int nn = t >> 5, ln = t & 31;
  float acc = b1[ln];
#pragma unroll
  for(int k = 0; k < 64; k++) acc += hs[nn][k]*w1[k*32 + ln];
  zs[nn][ln] = elu_f(acc);
  __syncthreads();
  int node = node0 + nn;
  if(ln < 2 && node < N){
    float o = b2[ln];
#pragma unroll
    for(int k = 0; k < 32; k++) o += zs[nn][k]*w2[k*2 + ln];
    out[(size_t)node*2 + ln] = o;
  }
}

// ---------------- launch ----------------

extern "C" void kernel_launch(void* const* d_in, const int* in_sizes, int n_in,
                              void* d_out, int out_size, void* d_ws, size_t ws_size,
                              hipStream_t stream)
{
  (void)n_in; (void)out_size; (void)ws_size;
  const float* x      = (const float*)d_in[0];
  const int*   ei     = (const int*)  d_in[1];
  const float* w_in   = (const float*)d_in[2];
  const float* b_in   = (const float*)d_in[3];
  const float* w_gcn  = (const float*)d_in[4];
  const float* b_gcn  = (const float*)d_in[5];
  const float* bn1_g  = (const float*)d_in[6];
  const float* bn1_b  = (const float*)d_in[7];
  const float* bn1_m  = (const float*)d_in[8];
  const float* bn1_v  = (const float*)d_in[9];
  const float* w_gat  = (const float*)d_in[10];
  const float* att_s  = (const float*)d_in[11];
  const float* att_d  = (const float*)d_in[12];
  const float* b_gat  = (const float*)d_in[13];
  const float* bn2_g  = (const float*)d_in[14];
  const float* bn2_b  = (const float*)d_in[15];
  const float* bn2_m  = (const float*)d_in[16];
  const float* bn2_v  = (const float*)d_in[17];
  const float* w_sl   = (const float*)d_in[18];
  const float* b_sage = (const float*)d_in[19];
  const float* w_sr   = (const float*)d_in[20];
  const float* bn3_g  = (const float*)d_in[21];
  const float* bn3_b  = (const float*)d_in[22];
  const float* bn3_m  = (const float*)d_in[23];
  const float* bn3_v  = (const float*)d_in[24];
  const float* w_res  = (const float*)d_in[25];
  const float* b_res  = (const float*)d_in[26];
  const float* w_c1   = (const float*)d_in[27];
  const float* b_c1   = (const float*)d_in[28];
  const float* w_c2   = (const float*)d_in[29];
  const float* b_c2   = (const float*)d_in[30];

  const int F_IN = 165;
  int N = in_sizes[0]/F_IN;
  int E = in_sizes[1]/2;
  const int* srcp = ei;
  const int* dstp = ei + E;

  char* p = (char*)d_ws;
  auto alloc = [&](size_t bytes) -> char* {
    char* q = p; p += (bytes + 255) & ~(size_t)255; return q;
  };
  ushort16* Acat  = (ushort16*)alloc((size_t)N*384*2);   // [mean_nb | h2 | h]
  ushort16* xb    = (ushort16*)alloc((size_t)N*192*2);   // later reused for h1
  ushort16* bufG  = (ushort16*)alloc((size_t)N*128*2);   // hw -> g -> (fp32 h3 overlays)
  float* a_src    = (float*)alloc((size_t)N*2*4);
  float* a_dst    = (float*)alloc((size_t)N*2*4);
  float* dinv     = (float*)alloc((size_t)N*4);
  int* cnt        = (int*)alloc((size_t)N*4);
  int* rowptr     = (int*)alloc((size_t)(N+1)*4);
  int* fill       = (int*)alloc((size_t)N*4);
  int* col        = (int*)alloc((size_t)E*4);
  float* s3       = (float*)alloc(64*4);
  float* bias3    = (float*)alloc(64*4);
  ushort16* pw_in  = (ushort16*)alloc(6*4*128*16);   // 48 KB
  ushort16* pw_gcn = (ushort16*)alloc(4*4*128*16);   // 32 KB
  ushort16* pw_gat = (ushort16*)alloc(4*4*128*16);
  ushort16* pw_cat = (ushort16*)alloc(12*4*64*16);   // 48 KB

  ushort16* h1 = xb;                 // xb dead after L0
  float*    h3 = (float*)bufG;       // g dead after gat_agg

  hipMemsetAsync(cnt,  0, (size_t)N*4, stream);
  hipMemsetAsync(fill, 0, (size_t)N*4, stream);

  count_deg_kernel<<<(E+255)/256, 256, 0, stream>>>(dstp, E, cnt);
  scan_kernel<<<1, 1024, 0, stream>>>(cnt, N, rowptr);
  dinv_kernel<<<(N+255)/256, 256, 0, stream>>>(cnt, dinv, N);
  scatter_kernel<<<(E+255)/256, 256, 0, stream>>>(srcp, dstp, E, rowptr, fill, col);

  cvt_x<<<N, 192, 0, stream>>>(x, xb, N);
  prep3<<<1, 64, 0, stream>>>(bn3_g, bn3_b, bn3_m, bn3_v, b_sage, b_res, s3, bias3);
  pack_w<<<(192*128+255)/256, 256, 0, stream>>>(w_in, 165, 128, 0, 192, nullptr, pw_in);
  pack_w<<<(128*128+255)/256, 256, 0, stream>>>(w_gcn, 128, 128, 0, 128, nullptr, pw_gcn);
  pack_w<<<(128*128+255)/256, 256, 0, stream>>>(w_gat, 128, 128, 0, 128, nullptr, pw_gat);
  pack_w<<<(128*64+255)/256, 256, 0, stream>>>(w_sl, 128, 64, 0,   128, s3,      pw_cat);
  pack_w<<<(128*64+255)/256, 256, 0, stream>>>(w_sr, 128, 64, 128, 128, s3,      pw_cat);
  pack_w<<<(128*64+255)/256, 256, 0, stream>>>(w_res,128, 64, 256, 128, nullptr, pw_cat);

  int g128 = (N + 127)/128;
  int g256 = (N + 255)/256;

  // h = elu(x@w_in + b_in)  -> Acat[:,256:384]
  mfma_gemm<6,128,1><<<g128, 256, 0, stream>>>(xb, 192, (const uint4v*)pw_in, b_in,
                                               (void*)(Acat + 256), 384, N);
  // hw = h@w_gcn -> bufG
  mfma_gemm<4,128,0><<<g128, 256, 0, stream>>>(Acat + 256, 384, (const uint4v*)pw_gcn, nullptr,
                                               (void*)bufG, 128, N);
  // h1 = elu(bn1(agg(hw) + b_gcn))
  gcn_agg<<<N, 64, 0, stream>>>((const uint32*)bufG, rowptr, col, dinv, b_gcn,
                                bn1_g, bn1_b, bn1_m, bn1_v, (uint32*)h1, N);
  // g = h1@w_gat -> bufG
  mfma_gemm<4,128,0><<<g128, 256, 0, stream>>>(h1, 128, (const uint4v*)pw_gat, nullptr,
                                               (void*)bufG, 128, N);
  att_kernel<<<N, 64, 0, stream>>>((const uint32*)bufG, att_s, att_d, a_src, a_dst, N);
  // h2 -> Acat[:,128:256]
  gat_agg<<<N, 64, 0, stream>>>((const uint32*)bufG, a_src, a_dst, rowptr, col, b_gat,
                                bn2_g, bn2_b, bn2_m, bn2_v, (uint32*)Acat + 64, N);
  // mean_nb -> Acat[:,0:128]
  sage_mean<<<N, 64, 0, stream>>>((const uint32*)Acat + 64, rowptr, col, (uint32*)Acat, N);
  // h3 = elu((Acat @ [w_sl*s; w_sr*s; w_res]) + bias3)   (bn3 folded)
  mfma_gemm<12,64,2><<<g256, 256, 0, stream>>>(Acat, 384, (const uint4v*)pw_cat, bias3,
                                               (void*)h3, 64, N);
  classifier_kernel<<<(N+7)/8, 256, 0, stream>>>(h3, w_c1, b_c1, w_c2, b_c2, (float*)d_out, N);
}

// Round 3
// 400.430 us; speedup vs baseline: 2.8734x; 1.2838x over previous
//
#include <hip/hip_runtime.h>
#include <cstdint>
#include <cstddef>

#define BN_EPS 1e-5f

typedef __attribute__((ext_vector_type(8))) short short8v;
typedef __attribute__((ext_vector_type(4))) float float4v;
typedef __attribute__((ext_vector_type(4))) unsigned int uint4v;
typedef unsigned int uint32;
typedef unsigned short ushort16;

__device__ __forceinline__ float elu_f(float v){ return v > 0.f ? v : expm1f(v); }
__device__ __forceinline__ float leaky_f(float v){ return v > 0.f ? v : 0.2f*v; }
__device__ __forceinline__ uint32 f2bf(float f){
  uint32 b = __float_as_uint(f);
  return (b + 0x7fffu + ((b >> 16) & 1u)) >> 16;        // RNE
}
__device__ __forceinline__ float bflo(uint32 u){ return __uint_as_float(u << 16); }
__device__ __forceinline__ float bfhi(uint32 u){ return __uint_as_float(u & 0xffff0000u); }

// ---------------- graph preprocessing: CSR by dst ----------------

__global__ void count_deg_kernel(const int* __restrict__ dst, int E, int* __restrict__ cnt){
  int i = blockIdx.x*blockDim.x + threadIdx.x;
  if(i < E) atomicAdd(&cnt[dst[i]], 1);
}

// phase 1: per-block (1024-wide) exclusive scan + block sums
__global__ __launch_bounds__(1024) void scan_blocks(const int* __restrict__ cnt, int n,
                                                    int* __restrict__ part, int* __restrict__ bsum){
  __shared__ int wsum[16];
  int tid = threadIdx.x, lane = tid & 63, w = tid >> 6;
  int i = blockIdx.x*1024 + tid;
  int v = (i < n) ? cnt[i] : 0;
  int sv = v;
#pragma unroll
  for(int o = 1; o < 64; o <<= 1){
    int u = __shfl_up(sv, o);
    if(lane >= o) sv += u;
  }
  if(lane == 63) wsum[w] = sv;
  __syncthreads();
  int woff = 0;
#pragma unroll
  for(int q = 0; q < 16; q++) woff += (q < w) ? wsum[q] : 0;
  if(i < n) part[i] = woff + sv - v;          // exclusive within block
  if(tid == 1023) bsum[blockIdx.x] = woff + sv;  // block total
}

// phase 2: single block scans block sums (nb <= 1024), writes rowptr[n] = total
__global__ __launch_bounds__(1024) void scan_bsum(const int* __restrict__ bsum, int nb,
                                                  int* __restrict__ boff, int* __restrict__ rowptr, int n){
  __shared__ int wsum[16];
  int tid = threadIdx.x, lane = tid & 63, w = tid >> 6;
  int v = (tid < nb) ? bsum[tid] : 0;
  int sv = v;
#pragma unroll
  for(int o = 1; o < 64; o <<= 1){
    int u = __shfl_up(sv, o);
    if(lane >= o) sv += u;
  }
  if(lane == 63) wsum[w] = sv;
  __syncthreads();
  int woff = 0;
#pragma unroll
  for(int q = 0; q < 16; q++) woff += (q < w) ? wsum[q] : 0;
  if(tid < nb) boff[tid] = woff + sv - v;
  if(tid == 1023) rowptr[n] = woff + sv;
}

// phase 3: assemble rowptr; fused dinv
__global__ void scan_add_dinv(const int* __restrict__ part, const int* __restrict__ boff,
                              const int* __restrict__ cnt, int n,
                              int* __restrict__ rowptr, float* __restrict__ dinv){
  int i = blockIdx.x*blockDim.x + threadIdx.x;
  if(i < n){
    rowptr[i] = part[i] + boff[i >> 10];
    dinv[i] = rsqrtf((float)cnt[i] + 1.0f);   // deg includes self loop
  }
}

__global__ void scatter_kernel(const int* __restrict__ src, const int* __restrict__ dst, int E,
                               const int* __restrict__ rowptr, int* __restrict__ fill, int* __restrict__ col){
  int i = blockIdx.x*blockDim.x + threadIdx.x;
  if(i < E){
    int d = dst[i];
    int pos = rowptr[d] + atomicAdd(&fill[d], 1);
    col[pos] = src[i];
  }
}

// ---------------- x -> bf16, K padded 165 -> 192 ----------------

__global__ __launch_bounds__(192) void cvt_x(const float* __restrict__ x, ushort16* __restrict__ xb, int N){
  int i = blockIdx.x, t = threadIdx.x;
  float v = (t < 165) ? x[(size_t)i*165 + t] : 0.f;
  xb[(size_t)i*192 + t] = (ushort16)f2bf(v);
}

// ---------------- weight packing (one launch): packed[kgrp][col][8] bf16 ----------------

__device__ __forceinline__ void pack_region(const float* __restrict__ W, int K, int NOUT, int kbase, int idx,
                                            const float* __restrict__ scale, ushort16* __restrict__ out){
  int k = idx / NOUT, c = idx - k*NOUT;
  float v = (k < K) ? W[(size_t)k*NOUT + c] : 0.f;
  if(scale) v *= scale[c];
  int pk = kbase + k;
  out[(size_t)(pk >> 3)*NOUT*8 + (size_t)c*8 + (pk & 7)] = (ushort16)f2bf(v);
}

__global__ __launch_bounds__(256) void pack_all(const float* __restrict__ w_in, const float* __restrict__ w_gcn,
    const float* __restrict__ w_gat, const float* __restrict__ w_sl, const float* __restrict__ w_sr,
    const float* __restrict__ w_res, const float* __restrict__ s3,
    ushort16* __restrict__ pw_in, ushort16* __restrict__ pw_gcn,
    ushort16* __restrict__ pw_gat, ushort16* __restrict__ pw_cat){
  int b = blockIdx.x, t = threadIdx.x;
  if(b < 96)       pack_region(w_in,  165, 128, 0,   b*256 + t,        nullptr, pw_in);
  else if(b < 160) pack_region(w_gcn, 128, 128, 0,   (b-96)*256 + t,   nullptr, pw_gcn);
  else if(b < 224) pack_region(w_gat, 128, 128, 0,   (b-160)*256 + t,  nullptr, pw_gat);
  else if(b < 256) pack_region(w_sl,  128, 64,  0,   (b-224)*256 + t,  s3,      pw_cat);
  else if(b < 288) pack_region(w_sr,  128, 64,  128, (b-256)*256 + t,  s3,      pw_cat);
  else             pack_region(w_res, 128, 64,  256, (b-288)*256 + t,  nullptr, pw_cat);
}

// bn3 scale + combined bias for the fused SAGE epilogue
__global__ void prep3(const float* __restrict__ bg, const float* __restrict__ bb,
                      const float* __restrict__ bm, const float* __restrict__ bv,
                      const float* __restrict__ b_sage, const float* __restrict__ b_res,
                      float* __restrict__ s3, float* __restrict__ bias3){
  int c = threadIdx.x;   // 64
  float s = bg[c]*rsqrtf(bv[c] + BN_EPS);
  s3[c] = s;
  bias3[c] = (b_sage[c] - bm[c])*s + bb[c] + b_res[c];
}

// ---------------- MFMA bf16 GEMM ----------------
// out[M x NOUT] = epi(A[M x K] @ W)   A bf16 row-major (lda elements), W packed in global.
// EPI: 0 = raw -> bf16, 1 = bias+elu -> bf16, 2 = bias+elu -> fp32
// NOUT=128: 4 waves 2x2, tile 128x128. NOUT=64: 4 waves 4x1, tile 256x64.

template<int KSTEPS, int NOUT, int EPI>
__global__ __launch_bounds__(256) void mfma_gemm(
    const ushort16* __restrict__ A, int lda,
    const uint4v* __restrict__ pw,
    const float* __restrict__ bias,
    void* __restrict__ out, int ldo, int N)
{
  constexpr int LDSV = KSTEPS*4*NOUT;         // uint4 entries (16 B each)
  __shared__ uint4v wlds[LDSV];
  int t = threadIdx.x;
#pragma unroll
  for(int q = 0; q < LDSV/256; q++)
    wlds[q*256 + t] = pw[q*256 + t];
  __syncthreads();

  int wid = t >> 6, lane = t & 63;
  int wm, wn;
  if(NOUT == 128){ wm = wid >> 1; wn = wid & 1; } else { wm = wid; wn = 0; }
  constexpr int MTILE = (NOUT == 128) ? 128 : 256;
  long row0 = (long)blockIdx.x*MTILE + wm*64;
  int l15 = lane & 15, lk = lane >> 4;
  int wn64 = wn*64;
  const ushort16* wl = (const ushort16*)wlds;

  float4v acc[4][4];
#pragma unroll
  for(int fm = 0; fm < 4; fm++)
#pragma unroll
    for(int fn = 0; fn < 4; fn++) acc[fm][fn] = (float4v){0.f,0.f,0.f,0.f};

  const ushort16* abase[4];
#pragma unroll
  for(int fm = 0; fm < 4; fm++){
    long r = row0 + fm*16 + l15;
    if(r > (long)N - 1) r = (long)N - 1;
    abase[fm] = A + r*(size_t)lda + lk*8;
  }

  short8v a[4];
#pragma unroll
  for(int fm = 0; fm < 4; fm++) a[fm] = *(const short8v*)(abase[fm]);

#pragma unroll
  for(int ks = 0; ks < KSTEPS; ks++){
    short8v b[4];
#pragma unroll
    for(int fn = 0; fn < 4; fn++){
      int c = wn64 + fn*16 + l15;
      b[fn] = *(const short8v*)(wl + ((size_t)((ks*4 + lk)*NOUT + c))*8);
    }
    short8v an[4];
    if(ks + 1 < KSTEPS){
#pragma unroll
      for(int fm = 0; fm < 4; fm++) an[fm] = *(const short8v*)(abase[fm] + (ks + 1)*32);
    }
#pragma unroll
    for(int fm = 0; fm < 4; fm++)
#pragma unroll
      for(int fn = 0; fn < 4; fn++)
        acc[fm][fn] = __builtin_amdgcn_mfma_f32_16x16x32_bf16(a[fm], b[fn], acc[fm][fn], 0, 0, 0);
    if(ks + 1 < KSTEPS){
#pragma unroll
      for(int fm = 0; fm < 4; fm++) a[fm] = an[fm];
    }
  }

  // C/D layout: col = lane&15, row = (lane>>4)*4 + reg  [m89 verified]
#pragma unroll
  for(int fm = 0; fm < 4; fm++){
#pragma unroll
    for(int rr = 0; rr < 4; rr++){
      long r = row0 + fm*16 + lk*4 + rr;
      if(r < N){
#pragma unroll
        for(int fn = 0; fn < 4; fn++){
          int c = wn64 + fn*16 + l15;
          float v = acc[fm][fn][rr];
          if constexpr(EPI >= 1){ v += bias[c]; v = elu_f(v); }
          if constexpr(EPI == 2) ((float*)out)[r*(size_t)ldo + c] = v;
          else ((ushort16*)out)[r*(size_t)ldo + c] = (ushort16)f2bf(v);
        }
      }
    }
  }
}

// ---------------- GCN aggregation + BN1 + ELU (bf16 in/out, 2 ch/lane) ----------------

__global__ __launch_bounds__(64) void gcn_agg(const uint32* __restrict__ hw,   // stride 64 uints
    const int* __restrict__ rowptr, const int* __restrict__ col, const float* __restrict__ dinv,
    const float* __restrict__ b, const float* __restrict__ bg, const float* __restrict__ bb,
    const float* __restrict__ bm, const float* __restrict__ bv,
    uint32* __restrict__ h1, int N)
{
  __shared__ int sbuf[64];
  __shared__ float dbuf[64];
  int i = blockIdx.x, t = threadIdx.x;
  float di = dinv[i];
  int beg = rowptr[i], end = rowptr[i+1];
  uint32 u = hw[(size_t)i*64 + t];
  float a0 = bflo(u)*di, a1 = bfhi(u)*di;   // self loop
  for(int c0 = beg; c0 < end; c0 += 64){
    int p = c0 + t;
    int s = 0; float ds = 0.f;
    if(p < end){ s = col[p]; ds = dinv[s]; }
    sbuf[t] = s; dbuf[t] = ds;
    __syncthreads();
    int cl = min(64, end - c0);
    for(int q = 0; q < cl; q++){
      uint32 w = hw[(size_t)sbuf[q]*64 + t];
      float ds2 = dbuf[q];
      a0 += bflo(w)*ds2; a1 += bfhi(w)*ds2;
    }
    __syncthreads();
  }
  int c0i = 2*t, c1i = 2*t + 1;
  float v0 = a0*di + b[c0i], v1 = a1*di + b[c1i];
  v0 = elu_f((v0 - bm[c0i])*(bg[c0i]*rsqrtf(bv[c0i] + BN_EPS)) + bb[c0i]);
  v1 = elu_f((v1 - bm[c1i])*(bg[c1i]*rsqrtf(bv[c1i] + BN_EPS)) + bb[c1i]);
  h1[(size_t)i*64 + t] = f2bf(v0) | (f2bf(v1) << 16);
}

// ---------------- GAT attention scalars ----------------

__global__ __launch_bounds__(64) void att_kernel(const uint32* __restrict__ g,
    const float* __restrict__ att_s, const float* __restrict__ att_d,
    float* __restrict__ a_src, float* __restrict__ a_dst, int N)
{
  int i = blockIdx.x, t = threadIdx.x;
  uint32 u = g[(size_t)i*64 + t];
  float g0 = bflo(u), g1 = bfhi(u);
  float2 as2 = ((const float2*)att_s)[t];
  float2 ad2 = ((const float2*)att_d)[t];
  float s1 = g0*as2.x + g1*as2.y;
  float s2 = g0*ad2.x + g1*ad2.y;
#pragma unroll
  for(int o = 16; o > 0; o >>= 1){ s1 += __shfl_xor(s1, o); s2 += __shfl_xor(s2, o); }
  if((t & 31) == 0){ int h = t >> 5; a_src[2*i + h] = s1; a_dst[2*i + h] = s2; }
}

// ---------------- GAT softmax + weighted agg + BN2 + ELU ----------------
// writes h2 (bf16) into Acat[:,128:256]  (out pre-offset, stride 192 uints)

__global__ __launch_bounds__(64) void gat_agg(const uint32* __restrict__ g,   // stride 64
    const float* __restrict__ a_src, const float* __restrict__ a_dst,
    const int* __restrict__ rowptr, const int* __restrict__ col,
    const float* __restrict__ b_gat, const float* __restrict__ bg, const float* __restrict__ bb,
    const float* __restrict__ bm, const float* __restrict__ bv,
    uint32* __restrict__ h2out, int N)
{
  __shared__ int sbuf[64];
  __shared__ float w0buf[64], w1buf[64];
  int i = blockIdx.x, t = threadIdx.x;
  int beg = rowptr[i], end = rowptr[i+1];
  int deg = end - beg;
  float2 ad  = ((const float2*)a_dst)[i];
  float2 asv = ((const float2*)a_src)[i];
  float es0 = leaky_f(asv.x + ad.x), es1 = leaky_f(asv.y + ad.y);
  int h = t >> 5;
  float acc0, acc1, D0, D1;

  if(deg <= 64){
    // ---- fast path: one exp per edge per head, weights staged in LDS ----
    float l0 = -1e30f, l1 = -1e30f;
    if(t < deg){
      int s = col[beg + t];
      sbuf[t] = s;
      float2 a = ((const float2*)a_src)[s];
      l0 = leaky_f(a.x + ad.x); l1 = leaky_f(a.y + ad.y);
    }
    float m0 = fmaxf(l0, es0), m1 = fmaxf(l1, es1);
#pragma unroll
    for(int o = 32; o > 0; o >>= 1){ m0 = fmaxf(m0, __shfl_xor(m0, o)); m1 = fmaxf(m1, __shfl_xor(m1, o)); }
    float e0 = (t < deg) ? __expf(l0 - m0) : 0.f;
    float e1 = (t < deg) ? __expf(l1 - m1) : 0.f;
    w0buf[t] = e0; w1buf[t] = e1;
    float d0 = e0, d1 = e1;
#pragma unroll
    for(int o = 32; o > 0; o >>= 1){ d0 += __shfl_xor(d0, o); d1 += __shfl_xor(d1, o); }
    d0 += __expf(es0 - m0); d1 += __expf(es1 - m1);   // self term
    D0 = d0 + 1e-16f; D1 = d1 + 1e-16f;
    __syncthreads();
    float Mh = h ? m1 : m0;
    float ws = __expf((h ? es1 : es0) - Mh);
    uint32 u = g[(size_t)i*64 + t];
    acc0 = ws*bflo(u); acc1 = ws*bfhi(u);
    for(int q = 0; q < deg; q++){
      uint32 v = g[(size_t)sbuf[q]*64 + t];
      float wgt = h ? w1buf[q] : w0buf[q];
      acc0 += wgt*bflo(v); acc1 += wgt*bfhi(v);
    }
  } else {
    // ---- generic path (deg > 64) ----
    float m0 = es0, m1 = es1;
    for(int p = beg + t; p < end; p += 64){
      float2 a = ((const float2*)a_src)[col[p]];
      m0 = fmaxf(m0, leaky_f(a.x + ad.x));
      m1 = fmaxf(m1, leaky_f(a.y + ad.y));
    }
#pragma unroll
    for(int o = 32; o > 0; o >>= 1){ m0 = fmaxf(m0, __shfl_xor(m0, o)); m1 = fmaxf(m1, __shfl_xor(m1, o)); }
    float d0 = (t == 0) ? __expf(es0 - m0) : 0.f;
    float d1 = (t == 0) ? __expf(es1 - m1) : 0.f;
    float Mh = h ? m1 : m0;
    float adh = h ? ad.y : ad.x;
    uint32 u = g[(size_t)i*64 + t];
    float ws = __expf((h ? es1 : es0) - Mh);
    acc0 = ws*bflo(u); acc1 = ws*bfhi(u);
    for(int c0 = beg; c0 < end; c0 += 64){
      int p = c0 + t;
      float e0 = 0.f, e1 = 0.f;
      int s = 0;
      if(p < end){
        s = col[p];
        float2 a = ((const float2*)a_src)[s];
        e0 = __expf(leaky_f(a.x + ad.x) - m0);
        e1 = __expf(leaky_f(a.y + ad.y) - m1);
      }
      d0 += e0; d1 += e1;
      sbuf[t] = s; w0buf[t] = e0; w1buf[t] = e1;
      __syncthreads();
      int cl = min(64, end - c0);
      for(int q = 0; q < cl; q++){
        uint32 v = g[(size_t)sbuf[q]*64 + t];
        float wgt = h ? w1buf[q] : w0buf[q];
        acc0 += wgt*bflo(v); acc1 += wgt*bfhi(v);
      }
      __syncthreads();
    }
#pragma unroll
    for(int o = 32; o > 0; o >>= 1){ d0 += __shfl_xor(d0, o); d1 += __shfl_xor(d1, o); }
    D0 = d0 + 1e-16f; D1 = d1 + 1e-16f;
  }

  float Dh = h ? D1 : D0;
  int c0i = 2*t, c1i = 2*t + 1;
  float v0 = acc0/Dh + b_gat[c0i], v1 = acc1/Dh + b_gat[c1i];
  v0 = elu_f((v0 - bm[c0i])*(bg[c0i]*rsqrtf(bv[c0i] + BN_EPS)) + bb[c0i]);
  v1 = elu_f((v1 - bm[c1i])*(bg[c1i]*rsqrtf(bv[c1i] + BN_EPS)) + bb[c1i]);
  h2out[(size_t)i*192 + t] = f2bf(v0) | (f2bf(v1) << 16);
}

// ---------------- SAGE mean (no self loops), h2 -> mean_nb, both inside Acat ----------------

__global__ __launch_bounds__(64) void sage_mean(const uint32* __restrict__ h2,  // pre-offset +64, stride 192
    const int* __restrict__ rowptr, const int* __restrict__ col,
    uint32* __restrict__ mout, int N)                                           // stride 192
{
  __shared__ int sbuf[64];
  int i = blockIdx.x, t = threadIdx.x;
  int beg = rowptr[i], end = rowptr[i+1];
  float a0 = 0.f, a1 = 0.f;
  for(int c0 = beg; c0 < end; c0 += 64){
    int p = c0 + t;
    sbuf[t] = (p < end) ? col[p] : 0;
    __syncthreads();
    int cl = min(64, end - c0);
    for(int q = 0; q < cl; q++){
      uint32 u = h2[(size_t)sbuf[q]*192 + t];
      a0 += bflo(u); a1 += bfhi(u);
    }
    __syncthreads();
  }
  float inv = 1.f/fmaxf((float)(end - beg), 1.f);
  mout[(size_t)i*192 + t] = f2bf(a0*inv) | (f2bf(a1*inv) << 16);
}

// ---------------- classifier: out = elu(h3@w1+b1)@w2 + b2 ----------------

__global__ __launch_bounds__(256) void classifier_kernel(const float* __restrict__ h3,
    const float* __restrict__ w1, const float* __restrict__ b1,
    const float* __restrict__ w2, const float* __restrict__ b2,
    float* __restrict__ out, int N)
{
  __shared__ float hs[8][64];
  __shared__ float zs[8][32];
  int node0 = blockIdx.x*8;
  int t = threadIdx.x;
#pragma unroll
  for(int q = 0; q < 2; q++){
    int e = t + q*256;
    int r = e >> 6, c = e & 63;
    int nd = node0 + r;
    hs[r][c] = (nd < N) ? h3[(size_t)nd*64 + c] : 0.f;
  }
  __syncthreads();
  int nn = t >> 5, ln = t & 31;
  float acc = b1[ln];
#pragma unroll
  for(int k = 0; k < 64; k++) acc += hs[nn][k]*w1[k*32 + ln];
  zs[nn][ln] = elu_f(acc);
  __syncthreads();
  int node = node0 + nn;
  if(ln < 2 && node < N){
    float o = b2[ln];
#pragma unroll
    for(int k = 0; k < 32; k++) o += zs[nn][k]*w2[k*2 + ln];
    out[(size_t)node*2 + ln] = o;
  }
}

// ---------------- launch ----------------

extern "C" void kernel_launch(void* const* d_in, const int* in_sizes, int n_in,
                              void* d_out, int out_size, void* d_ws, size_t ws_size,
                              hipStream_t stream)
{
  (void)n_in; (void)out_size; (void)ws_size;
  const float* x      = (const float*)d_in[0];
  const int*   ei     = (const int*)  d_in[1];
  const float* w_in   = (const float*)d_in[2];
  const float* b_in   = (const float*)d_in[3];
  const float* w_gcn  = (const float*)d_in[4];
  const float* b_gcn  = (const float*)d_in[5];
  const float* bn1_g  = (const float*)d_in[6];
  const float* bn1_b  = (const float*)d_in[7];
  const float* bn1_m  = (const float*)d_in[8];
  const float* bn1_v  = (const float*)d_in[9];
  const float* w_gat  = (const float*)d_in[10];
  const float* att_s  = (const float*)d_in[11];
  const float* att_d  = (const float*)d_in[12];
  const float* b_gat  = (const float*)d_in[13];
  const float* bn2_g  = (const float*)d_in[14];
  const float* bn2_b  = (const float*)d_in[15];
  const float* bn2_m  = (const float*)d_in[16];
  const float* bn2_v  = (const float*)d_in[17];
  const float* w_sl   = (const float*)d_in[18];
  const float* b_sage = (const float*)d_in[19];
  const float* w_sr   = (const float*)d_in[20];
  const float* bn3_g  = (const float*)d_in[21];
  const float* bn3_b  = (const float*)d_in[22];
  const float* bn3_m  = (const float*)d_in[23];
  const float* bn3_v  = (const float*)d_in[24];
  const float* w_res  = (const float*)d_in[25];
  const float* b_res  = (const float*)d_in[26];
  const float* w_c1   = (const float*)d_in[27];
  const float* b_c1   = (const float*)d_in[28];
  const float* w_c2   = (const float*)d_in[29];
  const float* b_c2   = (const float*)d_in[30];

  const int F_IN = 165;
  int N = in_sizes[0]/F_IN;
  int E = in_sizes[1]/2;
  const int* srcp = ei;
  const int* dstp = ei + E;
  int nb = (N + 1023) >> 10;

  char* p = (char*)d_ws;
  auto alloc = [&](size_t bytes) -> char* {
    char* q = p; p += (bytes + 255) & ~(size_t)255; return q;
  };
  ushort16* Acat  = (ushort16*)alloc((size_t)N*384*2);   // [mean_nb | h2 | h]
  ushort16* xb    = (ushort16*)alloc((size_t)N*192*2);   // later reused for h1
  ushort16* bufG  = (ushort16*)alloc((size_t)N*128*2);   // hw -> g -> (fp32 h3 overlays)
  float* a_src    = (float*)alloc((size_t)N*2*4);
  float* a_dst    = (float*)alloc((size_t)N*2*4);
  float* dinv     = (float*)alloc((size_t)N*4);
  int* cnt        = (int*)alloc((size_t)N*4);
  int* fill       = (int*)alloc((size_t)N*4);
  int* rowptr     = (int*)alloc((size_t)(N+1)*4);
  int* part       = (int*)alloc((size_t)N*4);
  int* bsum       = (int*)alloc(1024*4);
  int* boff       = (int*)alloc(1024*4);
  int* col        = (int*)alloc((size_t)E*4);
  float* s3       = (float*)alloc(64*4);
  float* bias3    = (float*)alloc(64*4);
  ushort16* pw_in  = (ushort16*)alloc(6*4*128*16);   // 48 KB
  ushort16* pw_gcn = (ushort16*)alloc(4*4*128*16);   // 32 KB
  ushort16* pw_gat = (ushort16*)alloc(4*4*128*16);
  ushort16* pw_cat = (ushort16*)alloc(12*4*64*16);   // 48 KB

  ushort16* h1 = xb;                 // xb dead after L0
  float*    h3 = (float*)bufG;       // g dead after gat_agg

  // cnt and fill are adjacent allocations: one memset covers both (incl. pad)
  hipMemsetAsync(cnt, 0, (size_t)((char*)(fill + N) - (char*)cnt), stream);

  count_deg_kernel<<<(E+255)/256, 256, 0, stream>>>(dstp, E, cnt);
  scan_blocks<<<nb, 1024, 0, stream>>>(cnt, N, part, bsum);
  scan_bsum<<<1, 1024, 0, stream>>>(bsum, nb, boff, rowptr, N);
  scan_add_dinv<<<(N+255)/256, 256, 0, stream>>>(part, boff, cnt, N, rowptr, dinv);
  scatter_kernel<<<(E+255)/256, 256, 0, stream>>>(srcp, dstp, E, rowptr, fill, col);

  cvt_x<<<N, 192, 0, stream>>>(x, xb, N);
  prep3<<<1, 64, 0, stream>>>(bn3_g, bn3_b, bn3_m, bn3_v, b_sage, b_res, s3, bias3);
  pack_all<<<320, 256, 0, stream>>>(w_in, w_gcn, w_gat, w_sl, w_sr, w_res, s3,
                                    pw_in, pw_gcn, pw_gat, pw_cat);

  int g128 = (N + 127)/128;
  int g256 = (N + 255)/256;

  // h = elu(x@w_in + b_in)  -> Acat[:,256:384]
  mfma_gemm<6,128,1><<<g128, 256, 0, stream>>>(xb, 192, (const uint4v*)pw_in, b_in,
                                               (void*)(Acat + 256), 384, N);
  // hw = h@w_gcn -> bufG
  mfma_gemm<4,128,0><<<g128, 256, 0, stream>>>(Acat + 256, 384, (const uint4v*)pw_gcn, nullptr,
                                               (void*)bufG, 128, N);
  // h1 = elu(bn1(agg(hw) + b_gcn))
  gcn_agg<<<N, 64, 0, stream>>>((const uint32*)bufG, rowptr, col, dinv, b_gcn,
                                bn1_g, bn1_b, bn1_m, bn1_v, (uint32*)h1, N);
  // g = h1@w_gat -> bufG
  mfma_gemm<4,128,0><<<g128, 256, 0, stream>>>(h1, 128, (const uint4v*)pw_gat, nullptr,
                                               (void*)bufG, 128, N);
  att_kernel<<<N, 64, 0, stream>>>((const uint32*)bufG, att_s, att_d, a_src, a_dst, N);
  // h2 -> Acat[:,128:256]
  gat_agg<<<N, 64, 0, stream>>>((const uint32*)bufG, a_src, a_dst, rowptr, col, b_gat,
                                bn2_g, bn2_b, bn2_m, bn2_v, (uint32*)Acat + 64, N);
  // mean_nb -> Acat[:,0:128]
  sage_mean<<<N, 64, 0, stream>>>((const uint32*)Acat + 64, rowptr, col, (uint32*)Acat, N);
  // h3 = elu((Acat @ [w_sl*s; w_sr*s; w_res]) + bias3)   (bn3 folded)
  mfma_gemm<12,64,2><<<g256, 256, 0, stream>>>(Acat, 384, (const uint4v*)pw_cat, bias3,
                                               (void*)h3, 64, N);
  classifier_kernel<<<(N+7)/8, 256, 0, stream>>>(h3, w_c1, b_c1, w_c2, b_c2, (float*)d_out, N);
}